// Round 9
// baseline (587.479 us; speedup 1.0000x reference)
//
#include <hip/hip_runtime.h>
#include <hip/hip_bf16.h>

// ---------------------------------------------------------------------------
// NanoGPT block on MI355X (gfx950). bf16 MFMA GEMMs, fp32 accumulate.
// Round 13: abandon the 8-phase qk8 detour (2 rounds, null vs 128^2 baseline
// at K=768 / 1-block-per-CU). QK^T reverted to the proven 128^2 MODE-5
// (149us, round 5). PV rebuilt as a dedicated 64x128-tile kernel:
//   - grid 12(d) x 32(q) x 4(z) = 1536 blocks at FULL K=4096 (64 iters,
//     deep-K amortization) -- fixes the 6-m-tile grid starvation that
//     split-K only papered over.
//   - LDS 24 KB, acc 8 f32x4 -> ~4 blocks/CU resident (was 1-2).
//   - no split-K partials: epilogue divides by Lsum directly (round-5
//     MODE-6 verified semantics); LN2 back to plain single-input.
// All kernels share the verified XOR-swizzle (conflicts 1.26e7 -> 0) and
// packed us4/float4 operand-swapped epilogues.
// ---------------------------------------------------------------------------

#define DDIM 768
#define TT   4096
#define NB   4
#define ROWS (NB * TT)   // 16384

using bf16 = __hip_bfloat16;
typedef __bf16 bf16x8 __attribute__((ext_vector_type(8)));
typedef float  f32x4  __attribute__((ext_vector_type(4)));
typedef unsigned short us4 __attribute__((ext_vector_type(4)));

__device__ __forceinline__ float to_f(float x) { return x; }
__device__ __forceinline__ float to_f(bf16 x) { return __bfloat162float(x); }

__device__ __forceinline__ unsigned short bfb(float f) {
  bf16 b = __float2bfloat16(f);
  return __builtin_bit_cast(unsigned short, b);
}

// Async global->LDS, 16B per lane. LDS dest is wave-uniform base + lane*16.
__device__ __forceinline__ void gload16(const void* g, void* l) {
#if __has_builtin(__builtin_amdgcn_global_load_lds)
  __builtin_amdgcn_global_load_lds(
      (const __attribute__((address_space(1))) void*)g,
      (__attribute__((address_space(3))) void*)l, 16, 0, 0);
#else
  int lane = threadIdx.x & 63;
  ((int4*)l)[lane] = *(const int4*)g;
#endif
}

// ---------------------------------------------------------------------------
// Generic batched GEMM: C[z] = A[z][M x K] * B[z][N x K]^T  (bf16 in)
// 128x128 tile per block, 256 threads = 4 waves (2x2), each wave 64x64
// (4x4 frags of 16x16x32). BK=64, swizzled LDS (conflict-free ds_read_b128).
// acc layout: rows (M dim) = quad*4+reg (4 consecutive), cols (N dim)=lane&15.
// All epilogues store OUTPUT[col][row] so the 4 regs pack into one 8B store.
// SWZ: 1 = n-fastest XCD swizzle; 2 = m-fastest.
// MODE 3: h[col][row] = relu(acc + bias[row]), bf16
// MODE 4: out[col][row] = acc + bias[row] + resid[col][row], fp32 (float4, nt)
// MODE 5: P[col][row] = exp2(acc*scale) bf16, row sums over M -> Lsum[col]
// ---------------------------------------------------------------------------
template <int MODE, int SWZ, int NT, int MT>
__global__ __launch_bounds__(256) void gemm_bt(
    const bf16* __restrict__ A, int lda, long sA,
    const bf16* __restrict__ B, int ldb, long sB,
    void* __restrict__ Cout, int ldc, long sC, int K, float scale,
    const float* __restrict__ bias, const float* __restrict__ resid,
    float* __restrict__ Lsum) {
  __shared__ __align__(16) bf16 As[128 * 64];   // 16 KB
  __shared__ __align__(16) bf16 Bs[128 * 64];   // 16 KB
  __shared__ float Lred[128];

  int bx, by, bz;
  if constexpr (SWZ == 1) {
    const int h   = blockIdx.x;
    const int xcd = h & 7;
    const int s   = h >> 3;
    bx = s % NT;                           // n cycles fastest within an XCD
    const int g = (s / NT) * 8 + xcd;      // (m,z) group pinned to this XCD
    by = g % MT;
    bz = g / MT;
  } else {
    const int h   = blockIdx.x;
    const int xcd = h & 7;
    const int s   = h >> 3;
    by = s % MT;                           // m cycles fastest within an XCD
    const int g = (s / MT) * 8 + xcd;      // (n,z) group pinned to this XCD
    bx = g % NT;
    bz = g / NT;
  }

  A += (long)bz * sA;
  B += (long)bz * sB;

  const int tid  = threadIdx.x;        // 0..255
  const int wave = tid >> 6;           // 0..3
  const int lane = tid & 63;
  const int l16  = lane & 15;
  const int lq   = lane >> 4;          // quad 0..3
  const int wm   = wave >> 1;          // wave row 0..1
  const int wn   = wave & 1;           // wave col 0..1
  const long tileM = (long)by * 128;
  const long tileN = (long)bx * 128;

  if constexpr (MODE == 5) {
    if (tid < 128) Lred[tid] = 0.f;
  }

  f32x4 acc[4][4] = {};

  // Staging: 16 chunks of 1KB per 16KB tile; chunk = q*4 + wave. Physical LDS
  // is linear; the swizzle lives in the global SOURCE address (involution:
  // byte ^= ((row&7)<<4); rows are 128B).
  unsigned int aoff[4], boff[4];
#pragma unroll
  for (int q = 0; q < 4; ++q) {
    const int p    = (q * 4 + wave) * 1024 + lane * 16;  // phys byte in tile
    const int lg   = p ^ (((p >> 7) & 7) << 4);          // logical byte
    const int row  = lg >> 7;
    const int colb = lg & 127;
    aoff[q] = (unsigned int)((tileM + row) * (long)lda * 2 + colb);
    boff[q] = (unsigned int)((tileN + row) * (long)ldb * 2 + colb);
  }

  const char* Ab = (const char*)A;
  const char* Bb = (const char*)B;
  char* AsB = (char*)As;
  char* BsB = (char*)Bs;
  const int sw = (l16 & 7) << 4;

  for (int kb = 0; kb < K * 2; kb += 128) {   // byte offset along K
#pragma unroll
    for (int q = 0; q < 4; ++q)
      gload16(Ab + (aoff[q] + kb), AsB + (q * 4 + wave) * 1024);
#pragma unroll
    for (int q = 0; q < 4; ++q)
      gload16(Bb + (boff[q] + kb), BsB + (q * 4 + wave) * 1024);
    __syncthreads();

#pragma unroll
    for (int kk = 0; kk < 2; ++kk) {
      bf16x8 af[4], bf_[4];
      const int ks = (kk * 64 + lq * 16) ^ sw;
#pragma unroll
      for (int i = 0; i < 4; ++i)
        af[i] = *(const bf16x8*)(AsB + (wm * 64 + i * 16 + l16) * 128 + ks);
#pragma unroll
      for (int j = 0; j < 4; ++j)
        bf_[j] = *(const bf16x8*)(BsB + (wn * 64 + j * 16 + l16) * 128 + ks);
#pragma unroll
      for (int i = 0; i < 4; ++i)
#pragma unroll
        for (int j = 0; j < 4; ++j)
          acc[i][j] = __builtin_amdgcn_mfma_f32_16x16x32_bf16(af[i], bf_[j],
                                                              acc[i][j], 0, 0, 0);
    }
    __syncthreads();
  }

  const long base_m = tileM + wm * 64;   // acc row dim (A rows)
  const long base_n = tileN + wn * 64;   // acc col dim (B rows)

  if constexpr (MODE == 5) {
    // A=K-matrix (rows=k), B=Q (rows=q). P[q][k], rowsum over k per q.
    bf16* P = (bf16*)Cout + (long)bz * sC;
    float ps[4] = {0.f, 0.f, 0.f, 0.f};
#pragma unroll
    for (int j = 0; j < 4; ++j) {
      const long colq = base_n + j * 16 + l16;
#pragma unroll
      for (int i = 0; i < 4; ++i) {
        const long krow = base_m + i * 16 + lq * 4;
        const float p0 = exp2f(acc[i][j][0] * scale);
        const float p1 = exp2f(acc[i][j][1] * scale);
        const float p2 = exp2f(acc[i][j][2] * scale);
        const float p3 = exp2f(acc[i][j][3] * scale);
        ps[j] += (p0 + p1) + (p2 + p3);
        us4 w = {bfb(p0), bfb(p1), bfb(p2), bfb(p3)};
        *(us4*)(P + colq * (long)ldc + krow) = w;
      }
    }
    // reduce partial sums over the quad dim (lanes 16,32 apart share l16);
    // two waves (wm=0,1) share each Lred slot -> atomicAdd.
#pragma unroll
    for (int j = 0; j < 4; ++j) {
      float v = ps[j];
      v += __shfl_xor(v, 16);
      v += __shfl_xor(v, 32);
      if (lq == 0) atomicAdd(&Lred[wn * 64 + j * 16 + l16], v);
    }
    __syncthreads();
    if (tid < 128) atomicAdd(&Lsum[(long)bz * TT + tileN + tid], Lred[tid]);
  } else if constexpr (MODE == 3) {
    // A=W (rows=out_d), B=activations (rows=token). h[tok][d]=relu(acc+b[d])
    bf16* Hp = (bf16*)Cout;
#pragma unroll
    for (int i = 0; i < 4; ++i) {
      const long drow = base_m + i * 16 + lq * 4;
      const f32x4 bv = *(const f32x4*)&bias[drow];
#pragma unroll
      for (int j = 0; j < 4; ++j) {
        const long colt = base_n + j * 16 + l16;
        float v0 = acc[i][j][0] + bv[0]; v0 = v0 > 0.f ? v0 : 0.f;
        float v1 = acc[i][j][1] + bv[1]; v1 = v1 > 0.f ? v1 : 0.f;
        float v2 = acc[i][j][2] + bv[2]; v2 = v2 > 0.f ? v2 : 0.f;
        float v3 = acc[i][j][3] + bv[3]; v3 = v3 > 0.f ? v3 : 0.f;
        us4 w = {bfb(v0), bfb(v1), bfb(v2), bfb(v3)};
        *(us4*)(Hp + colt * (long)ldc + drow) = w;
      }
    }
  } else {  // MODE 4
    // out[tok][d] = acc + bias[d] + resid[tok][d], fp32, float4 stores (nt:
    // 4 quad-lanes x 16B = full 64B line per row per instruction)
    float* Op = (float*)Cout;
#pragma unroll
    for (int i = 0; i < 4; ++i) {
      const long drow = base_m + i * 16 + lq * 4;
      const f32x4 bv = *(const f32x4*)&bias[drow];
#pragma unroll
      for (int j = 0; j < 4; ++j) {
        const long off = (base_n + j * 16 + l16) * (long)ldc + drow;
        const f32x4 rs = *(const f32x4*)&resid[off];
        f32x4 o;
        o[0] = acc[i][j][0] + bv[0] + rs[0];
        o[1] = acc[i][j][1] + bv[1] + rs[1];
        o[2] = acc[i][j][2] + bv[2] + rs[2];
        o[3] = acc[i][j][3] + bv[3] + rs[3];
        __builtin_nontemporal_store(o, (f32x4*)(Op + off));
      }
    }
  }
}

// ---------------------------------------------------------------------------
// Dedicated PV kernel: O[q][d] = (P . V) / Lsum[q].
// A = Vt (768 x ROWS, lda=ROWS, batch col offset bz*TT): rows = d.
// B = P  (per batch TT x TT, ldb=TT): rows = q.  C = A.B^T -> acc[d][q].
// 64(d) x 128(q) tile, FULL K=4096 (64 iters of BK=64). 256 thr = 4 waves
// (2x2), wave tile 32d x 64q = 2x4 frags. LDS 24 KB (A 8K + B 16K, one
// array so staging chunk ids are uniform), XOR-swizzled via global source.
// Grid 12 x 32 x 4 = 1536, m-fastest XCD swizzle (P q-panel pinned per XCD,
// 12 d-blocks share it through L2).
// ---------------------------------------------------------------------------
__global__ __launch_bounds__(256) void gemm_pv(
    const bf16* __restrict__ A, const bf16* __restrict__ B,
    bf16* __restrict__ O, const float* __restrict__ Lsum) {
  __shared__ __align__(16) bf16 S[(64 + 128) * 64];   // 24 KB: A then B

  const int h   = blockIdx.x;
  const int xcd = h & 7;
  const int s   = h >> 3;
  const int by  = s % 12;              // d-tile cycles fastest within XCD
  const int g   = (s / 12) * 8 + xcd;  // (q-tile, z) pinned to this XCD
  const int bx  = g % 32;
  const int bz  = g / 32;

  const char* Ab = (const char*)(A + (long)bz * TT);            // batch cols
  const char* Bb = (const char*)(B + (long)bz * (long)TT * TT);

  const int tid  = threadIdx.x;
  const int wave = tid >> 6;
  const int lane = tid & 63;
  const int l16  = lane & 15;
  const int lq   = lane >> 4;
  const int wm   = wave >> 1;          // d-half 0..1
  const int wn   = wave & 1;           // q-half 0..1
  const long tileM = (long)by * 64;    // d base
  const long tileN = (long)bx * 128;   // q base

  // Staging: 24 chunks of 1KB (A: 0..7, B: 8..23); chunk c = wave + 4*u.
  // Linear LDS dest; inverse-swizzled global source (byte^=((row&7)<<4)).
  const char* gsrc[6];
  int ldsoff[6];
#pragma unroll
  for (int u = 0; u < 6; ++u) {
    const int c = wave + 4 * u;
    ldsoff[u] = c * 1024;
    if (c < 8) {
      const int p    = c * 1024 + lane * 16;
      const int row  = p >> 7;                         // 0..63 (d)
      const int colb = (p & 127) ^ ((row & 7) << 4);
      gsrc[u] = Ab + (tileM + row) * (long)ROWS * 2 + colb;
    } else {
      const int p    = (c - 8) * 1024 + lane * 16;
      const int row  = p >> 7;                         // 0..127 (q)
      const int colb = (p & 127) ^ ((row & 7) << 4);
      gsrc[u] = Bb + (tileN + row) * (long)TT * 2 + colb;
    }
  }

  f32x4 acc[2][4] = {};
  char* Sb_ = (char*)S;
  const int sw = (l16 & 7) << 4;

  for (long kb = 0; kb < (long)TT * 2; kb += 128) {   // 64 iterations
#pragma unroll
    for (int u = 0; u < 6; ++u)
      gload16(gsrc[u] + kb, Sb_ + ldsoff[u]);
    __syncthreads();

#pragma unroll
    for (int kk = 0; kk < 2; ++kk) {
      bf16x8 af[2], bf_[4];
      const int ks = (kk * 64 + lq * 16) ^ sw;
#pragma unroll
      for (int i = 0; i < 2; ++i)
        af[i] = *(const bf16x8*)(Sb_ + (wm * 32 + i * 16 + l16) * 128 + ks);
#pragma unroll
      for (int j = 0; j < 4; ++j)
        bf_[j] = *(const bf16x8*)(Sb_ + 8192 +
                                  (wn * 64 + j * 16 + l16) * 128 + ks);
#pragma unroll
      for (int i = 0; i < 2; ++i)
#pragma unroll
        for (int j = 0; j < 4; ++j)
          acc[i][j] = __builtin_amdgcn_mfma_f32_16x16x32_bf16(af[i], bf_[j],
                                                              acc[i][j], 0, 0, 0);
    }
    __syncthreads();
  }

  // Epilogue: O[q][d] = acc / Lsum[q], packed 8B stores.
  bf16* Op = O + (long)bz * (long)TT * DDIM;
  float inv[4];
#pragma unroll
  for (int j = 0; j < 4; ++j)
    inv[j] = 1.0f / Lsum[(long)bz * TT + tileN + wn * 64 + j * 16 + l16];
#pragma unroll
  for (int j = 0; j < 4; ++j) {
    const long colq = tileN + wn * 64 + j * 16 + l16;
#pragma unroll
    for (int i = 0; i < 2; ++i) {
      const long drow = tileM + wm * 32 + i * 16 + lq * 4;
      us4 w = {bfb(acc[i][j][0] * inv[j]), bfb(acc[i][j][1] * inv[j]),
               bfb(acc[i][j][2] * inv[j]), bfb(acc[i][j][3] * inv[j])};
      *(us4*)(Op + colq * (long)DDIM + drow) = w;
    }
  }
}

// ---------------------------------------------------------------------------
// Fused QKV projection: grid.z selects {Q, K, V}. z=0,1: A=y1 (rows=token),
// B=W, plain store to Qm/Km. z=2: OPERANDS SWAPPED (A=Wv rows=out_d, B=y1)
// so Vt[d][tok] is written with tok as the lane-contiguous dim (coalesced).
// Same 4-wave / BK=64 / swizzled-LDS structure as gemm_bt.
// ---------------------------------------------------------------------------
__global__ __launch_bounds__(256) void gemm_qkv(
    const bf16* __restrict__ Y,
    const bf16* __restrict__ Wq, const bf16* __restrict__ Wk,
    const bf16* __restrict__ Wv, bf16* __restrict__ Qm,
    bf16* __restrict__ Km, bf16* __restrict__ Vt) {
  __shared__ __align__(16) bf16 As[128 * 64];
  __shared__ __align__(16) bf16 Bs[128 * 64];

  const int z = blockIdx.z;
  const bf16* Ap = (z == 2) ? Wv : Y;
  const bf16* Bp = (z == 0) ? Wq : (z == 1) ? Wk : Y;

  const int tid  = threadIdx.x;
  const int wave = tid >> 6;
  const int lane = tid & 63;
  const int l16  = lane & 15;
  const int lq   = lane >> 4;
  const int wm   = wave >> 1;
  const int wn   = wave & 1;
  const long tileM = (z == 2) ? (long)blockIdx.x * 128 : (long)blockIdx.y * 128;
  const long tileN = (z == 2) ? (long)blockIdx.y * 128 : (long)blockIdx.x * 128;

  unsigned int aoff[4], boff[4];
#pragma unroll
  for (int q = 0; q < 4; ++q) {
    const int p    = (q * 4 + wave) * 1024 + lane * 16;
    const int lg   = p ^ (((p >> 7) & 7) << 4);
    const int row  = lg >> 7;
    const int colb = lg & 127;
    aoff[q] = (unsigned int)((tileM + row) * (long)DDIM * 2 + colb);
    boff[q] = (unsigned int)((tileN + row) * (long)DDIM * 2 + colb);
  }

  f32x4 acc[4][4] = {};

  const char* Ab = (const char*)Ap;
  const char* Bb = (const char*)Bp;
  char* AsB = (char*)As;
  char* BsB = (char*)Bs;
  const int sw = (l16 & 7) << 4;

  for (int kb = 0; kb < DDIM * 2; kb += 128) {
#pragma unroll
    for (int q = 0; q < 4; ++q)
      gload16(Ab + (aoff[q] + kb), AsB + (q * 4 + wave) * 1024);
#pragma unroll
    for (int q = 0; q < 4; ++q)
      gload16(Bb + (boff[q] + kb), BsB + (q * 4 + wave) * 1024);
    __syncthreads();

#pragma unroll
    for (int kk = 0; kk < 2; ++kk) {
      bf16x8 af[4], bf_[4];
      const int ks = (kk * 64 + lq * 16) ^ sw;
#pragma unroll
      for (int i = 0; i < 4; ++i)
        af[i] = *(const bf16x8*)(AsB + (wm * 64 + i * 16 + l16) * 128 + ks);
#pragma unroll
      for (int j = 0; j < 4; ++j)
        bf_[j] = *(const bf16x8*)(BsB + (wn * 64 + j * 16 + l16) * 128 + ks);
#pragma unroll
      for (int i = 0; i < 4; ++i)
#pragma unroll
        for (int j = 0; j < 4; ++j)
          acc[i][j] = __builtin_amdgcn_mfma_f32_16x16x32_bf16(af[i], bf_[j],
                                                              acc[i][j], 0, 0, 0);
    }
    __syncthreads();
  }

  const long base_m = tileM + wm * 64;
  const long base_n = tileN + wn * 64;
  bf16* Cp = (z == 0) ? Qm : (z == 1) ? Km : Vt;
  const long ldo = (z < 2) ? (long)DDIM : (long)ROWS;
#pragma unroll
  for (int i = 0; i < 4; ++i)
#pragma unroll
    for (int j = 0; j < 4; ++j)
#pragma unroll
      for (int r = 0; r < 4; ++r) {
        const long row = base_m + i * 16 + lq * 4 + r;
        const long col = base_n + j * 16 + l16;
        Cp[row * ldo + col] = __float2bfloat16(acc[i][j][r]);
      }
}

// ---------------------------------------------------------------------------
// LayerNorm (faithful to buggy reference): y = (x - mu/sqrt(var)) * g + b,
// var unbiased (ddof=1). One block (256 thr) per 768-element row. Out bf16.
// Optionally zeroes Lzero[row] (the attention row-sum accumulator).
// ---------------------------------------------------------------------------
template <typename T>
__global__ __launch_bounds__(256) void ln_kernel(
    const T* __restrict__ in, const float* __restrict__ g,
    const float* __restrict__ beta, bf16* __restrict__ out,
    float* __restrict__ Lzero) {
  const long row = blockIdx.x;
  if (Lzero != nullptr && threadIdx.x == 0) Lzero[row] = 0.f;
  const T* xr = in + row * DDIM;
  const int t = threadIdx.x;
  float v0 = to_f(xr[t]), v1 = to_f(xr[t + 256]), v2 = to_f(xr[t + 512]);
  float s = v0 + v1 + v2;
  float q = v0 * v0 + v1 * v1 + v2 * v2;
#pragma unroll
  for (int o = 32; o; o >>= 1) {
    s += __shfl_down(s, o);
    q += __shfl_down(q, o);
  }
  __shared__ float sb[4], qb[4];
  if ((t & 63) == 0) { sb[t >> 6] = s; qb[t >> 6] = q; }
  __syncthreads();
  const float S = sb[0] + sb[1] + sb[2] + sb[3];
  const float Q = qb[0] + qb[1] + qb[2] + qb[3];
  const float mu  = S * (1.0f / 768.0f);
  const float var = (Q - 768.0f * mu * mu) * (1.0f / 767.0f);
  const float sub = mu / sqrtf(var);
  bf16* orow = out + row * DDIM;
  orow[t]       = __float2bfloat16((v0 - sub) * g[t]       + beta[t]);
  orow[t + 256] = __float2bfloat16((v1 - sub) * g[t + 256] + beta[t + 256]);
  orow[t + 512] = __float2bfloat16((v2 - sub) * g[t + 512] + beta[t + 512]);
}

// ---------------------------------------------------------------------------
// Weight prep: z=0..2 transpose+cast wq/wk/wv (K x N -> N x K bf16),
// z=3..4 straight cast fc1_w/fc2_w (already N x K).
// block (32,8), grid (24,24,5)
// ---------------------------------------------------------------------------
__global__ void prep_weights(const float* __restrict__ wq,
                             const float* __restrict__ wk,
                             const float* __restrict__ wv,
                             const float* __restrict__ f1,
                             const float* __restrict__ f2,
                             bf16* wqt, bf16* wkt, bf16* wvt, bf16* f1b,
                             bf16* f2b) {
  __shared__ float tile[32][33];
  const float* src;
  bf16* dst;
  bool tr = true;
  switch (blockIdx.z) {
    case 0: src = wq; dst = wqt; break;
    case 1: src = wk; dst = wkt; break;
    case 2: src = wv; dst = wvt; break;
    case 3: src = f1; dst = f1b; tr = false; break;
    default: src = f2; dst = f2b; tr = false; break;
  }
  const int tx = threadIdx.x, ty = threadIdx.y;
  const int x = blockIdx.x * 32 + tx;
  const int y = blockIdx.y * 32 + ty;
  if (tr) {
#pragma unroll
    for (int r = 0; r < 4; ++r) tile[ty + 8 * r][tx] = src[(y + 8 * r) * DDIM + x];
    __syncthreads();
    const int ox = blockIdx.y * 32 + tx;
    const int oy = blockIdx.x * 32 + ty;
#pragma unroll
    for (int r = 0; r < 4; ++r)
      dst[(oy + 8 * r) * DDIM + ox] = __float2bfloat16(tile[tx][ty + 8 * r]);
  } else {
#pragma unroll
    for (int r = 0; r < 4; ++r)
      dst[(y + 8 * r) * DDIM + x] = __float2bfloat16(src[(y + 8 * r) * DDIM + x]);
  }
}

// ---------------------------------------------------------------------------
extern "C" void kernel_launch(void* const* d_in, const int* in_sizes, int n_in,
                              void* d_out, int out_size, void* d_ws,
                              size_t ws_size, hipStream_t stream) {
  const float* x     = (const float*)d_in[0];
  const float* ln1_g = (const float*)d_in[1];
  const float* ln1_b = (const float*)d_in[2];
  const float* wq    = (const float*)d_in[3];
  const float* wk    = (const float*)d_in[4];
  const float* wv    = (const float*)d_in[5];
  const float* ln2_g = (const float*)d_in[6];
  const float* ln2_b = (const float*)d_in[7];
  const float* f1w   = (const float*)d_in[8];
  const float* f1bias= (const float*)d_in[9];
  const float* f2w   = (const float*)d_in[10];
  const float* f2bias= (const float*)d_in[11];
  float* out = (float*)d_out;

  char* ws = (char*)d_ws;
  size_t off = 0;
  auto take = [&](size_t bytes) -> char* {
    char* p = ws + off;
    off += (bytes + 255) & ~(size_t)255;
    return p;
  };
  const size_t WB = (size_t)DDIM * DDIM * sizeof(bf16);   // 1.18 MB
  const size_t MB = (size_t)ROWS * DDIM * sizeof(bf16);   // 25.2 MB
  bf16* wqt = (bf16*)take(WB);
  bf16* wkt = (bf16*)take(WB);
  bf16* wvt = (bf16*)take(WB);
  bf16* f1b = (bf16*)take(WB);
  bf16* f2b = (bf16*)take(WB);
  float* Lsum = (float*)take((size_t)ROWS * sizeof(float));  // softmax row sums
  bf16* y1  = (bf16*)take(MB);
  bf16* Qm  = (bf16*)take(MB);
  bf16* Km  = (bf16*)take(MB);
  bf16* Vt  = (bf16*)take(MB);                              // V^T: 768 x 16384
  bf16* Sb  = (bf16*)take((size_t)NB * TT * TT * sizeof(bf16));  // 134 MB (P)
  // buffer reuse (strictly sequential stream):
  //   O  = y1 (dead after QKV); LN2 reads y1 -> y2 = Qm (dead after QK^T);
  //   MLP hidden h = Km (dead after QK^T)
  bf16* O  = y1;
  bf16* y2 = Qm;
  bf16* h  = Km;

  prep_weights<<<dim3(24, 24, 5), dim3(32, 8), 0, stream>>>(
      wq, wk, wv, f1w, f2w, wqt, wkt, wvt, f1b, f2b);

  // LN1 also zeroes Lsum (must precede QK^T; ws is re-poisoned every call)
  ln_kernel<float><<<ROWS, 256, 0, stream>>>(x, ln1_g, ln1_b, y1, Lsum);

  // Fused QKV projections, 2304 blocks (z=2 operand-swapped for Vt)
  gemm_qkv<<<dim3(6, 128, 3), 256, 0, stream>>>(y1, wqt, wkt, wvt, Qm, Km, Vt);

  // scale folded with log2(e): P = exp2(log2e/sqrt(768) * K Q^T)
  const float scale2 = 0.03608439182435161f * 1.4426950408889634f;
  // SWAPPED: A=K (rows=k), B=Q (rows=q). P[q][k] + row sums -> Lsum.
  gemm_bt<5, 1, 32, 32><<<dim3(32 * 32 * NB), 256, 0, stream>>>(
      Km, DDIM, (long)TT * DDIM, Qm, DDIM, (long)TT * DDIM, Sb, TT,
      (long)TT * TT, DDIM, scale2, nullptr, nullptr, Lsum);

  // PV: dedicated 64x128-tile kernel, full K=4096, grid 1536, direct
  // Lsum-normalize in the epilogue (no split-K partials).
  gemm_pv<<<dim3(12 * 32 * NB), 256, 0, stream>>>(Vt, Sb, O, Lsum);

  ln_kernel<bf16><<<ROWS, 256, 0, stream>>>(O, ln2_g, ln2_b, y2, nullptr);

  // MLP, SWAPPED (A=weight rows=out_d, B=activation rows=token).
  // m-fastest swizzle: activation tile pinned in L2, weight tiles cycle.
  gemm_bt<3, 2, 128, 6><<<dim3(128 * 6), 256, 0, stream>>>(
      f1b, DDIM, 0, y2, DDIM, 0, h, DDIM, 0, DDIM, 1.f, f1bias, nullptr,
      nullptr);
  gemm_bt<4, 2, 128, 6><<<dim3(128 * 6), 256, 0, stream>>>(
      f2b, DDIM, 0, h, DDIM, 0, out, DDIM, 0, DDIM, 1.f, f2bias, x, nullptr);
}

// Round 10
// 545.919 us; speedup vs baseline: 1.0761x; 1.0761x over previous
//
#include <hip/hip_runtime.h>
#include <hip/hip_bf16.h>

// ---------------------------------------------------------------------------
// NanoGPT block on MI355X (gfx950). bf16 MFMA GEMMs, fp32 accumulate.
// Round 14 = revert to the round-8 champion (546.4 us measured best).
// Round 9's dedicated PV (64x128 tile) regressed -41us: 12 ds_read_b128 per
// 16 MFMA (0.75/MFMA) vs 0.5 for 128^2 -> LDS-pipe-bound (round-3 failure
// mode). Cross-container noise is +-8% (identical QK^T code: 149 vs 161us),
// so only the measured-best configuration is defensible:
//   - qk8: 256^2 8-phase counted-vmcnt QK^T (152us)
//   - split-K x2 PV on the 128^2 swizzled structure (1536 blocks, 6/CU)
//   - LN2 fuses (O0+O1)/Lsum; packed us4/float4 epilogues everywhere
//   - XOR-swizzled LDS everywhere (bank conflicts 1.26e7 -> 0, verified)
// ---------------------------------------------------------------------------

#define DDIM 768
#define TT   4096
#define NB   4
#define ROWS (NB * TT)   // 16384

using bf16 = __hip_bfloat16;
typedef __bf16 bf16x8 __attribute__((ext_vector_type(8)));
typedef float  f32x4  __attribute__((ext_vector_type(4)));
typedef unsigned short us4 __attribute__((ext_vector_type(4)));

__device__ __forceinline__ float to_f(float x) { return x; }
__device__ __forceinline__ float to_f(bf16 x) { return __bfloat162float(x); }

__device__ __forceinline__ unsigned short bfb(float f) {
  bf16 b = __float2bfloat16(f);
  return __builtin_bit_cast(unsigned short, b);
}

// Async global->LDS, 16B per lane. LDS dest is wave-uniform base + lane*16.
__device__ __forceinline__ void gload16(const void* g, void* l) {
#if __has_builtin(__builtin_amdgcn_global_load_lds)
  __builtin_amdgcn_global_load_lds(
      (const __attribute__((address_space(1))) void*)g,
      (__attribute__((address_space(3))) void*)l, 16, 0, 0);
#else
  int lane = threadIdx.x & 63;
  ((int4*)l)[lane] = *(const int4*)g;
#endif
}

// Phase-boundary primitives. Raw s_barrier (no vmcnt drain); sched_barrier
// pins compile-time ordering so MFMAs/ds_reads can't cross phase edges.
#define SBAR()                                        \
  do {                                                \
    __builtin_amdgcn_sched_barrier(0);                \
    asm volatile("s_barrier" ::: "memory");           \
    __builtin_amdgcn_sched_barrier(0);                \
  } while (0)
#define VMW3() asm volatile("s_waitcnt vmcnt(3)" ::: "memory")
#define VMW0() asm volatile("s_waitcnt vmcnt(0)" ::: "memory")

// 16 MFMA = one C-quadrant (4 i-frags x 2 j-frags x 2 k-slices), setprio'd.
template <int IH, int JH>
__device__ __forceinline__ void mmaQ(f32x4 (&acc)[8][4],
                                     const bf16x8 (&af)[4][2],
                                     const bf16x8 (&bfh)[2][2]) {
  __builtin_amdgcn_s_setprio(1);
#pragma unroll
  for (int ii = 0; ii < 4; ++ii)
#pragma unroll
    for (int jj = 0; jj < 2; ++jj)
#pragma unroll
      for (int kk = 0; kk < 2; ++kk)
        acc[IH * 4 + ii][JH * 2 + jj] = __builtin_amdgcn_mfma_f32_16x16x32_bf16(
            af[ii][kk], bfh[jj][kk], acc[IH * 4 + ii][JH * 2 + jj], 0, 0, 0);
  __builtin_amdgcn_s_setprio(0);
}

// ---------------------------------------------------------------------------
// 8-phase 256x256 QK^T: P[q][k] = exp2(scale * K Q^T), row sums -> Lsum[q].
// A=K-matrix (M dim = k), B=Q (N dim = q). 512 threads = 8 waves (2Mx4N);
// wave tile 128x64. LDS: A/B double-buffered 256x64 bf16 (128 KiB),
// XOR-swizzled content via pre-swizzled global source (linear lds dest).
// Stage units: 1 unit = 1 gload16/thread = 8KB = a 64-row quarter of a tile.
// Per phase exactly 2 units; vmcnt(3) at ph0/ph4 (in-order retirement:
// 3 units issued after the newest-needed one).
// ---------------------------------------------------------------------------
__global__ __launch_bounds__(512) void gemm_qk8(
    const bf16* __restrict__ A, int lda, long sA,
    const bf16* __restrict__ B, int ldb, long sB,
    bf16* __restrict__ Pout, int ldc, long sC, int K, float scale,
    float* __restrict__ Lsum) {
  __shared__ __align__(16) bf16 As[2][256 * 64];   // 64 KB
  __shared__ __align__(16) bf16 Bs[2][256 * 64];   // 64 KB

  // XCD swizzle: q-tiles (bx) cycle fastest within an XCD; (by,bz) pinned.
  const int h   = blockIdx.x;
  const int xcd = h & 7;
  const int s   = h >> 3;
  const int bx  = s % 16;
  const int g   = (s / 16) * 8 + xcd;
  const int by  = g % 16;
  const int bz  = g / 16;

  const char* Ab = (const char*)(A + (long)bz * sA);
  const char* Bb = (const char*)(B + (long)bz * sB);

  const int tid  = threadIdx.x;
  const int wave = tid >> 6;
  const int lane = tid & 63;
  const int l16  = lane & 15;
  const int lq   = lane >> 4;
  const int wm   = wave >> 2;          // 0..1 (M half)
  const int wn   = wave & 3;           // 0..3 (N quarter)
  const long tileM = (long)by * 256;
  const long tileN = (long)bx * 256;

  // Staging source map (involution byte^=((row&7)<<4), 128B rows).
  const int  pu  = wave * 1024 + lane * 16;
  const int  r0  = pu >> 7;
  const int  cc0 = (pu & 127) ^ ((r0 & 7) << 4);
  const long aoff   = (tileM + r0) * (long)lda * 2 + cc0;
  const long boff   = (tileN + r0) * (long)ldb * 2 + cc0;
  const long arow64 = 64 * (long)lda * 2;
  const long brow64 = 64 * (long)ldb * 2;
  char* As0 = (char*)As[0];
  char* As1 = (char*)As[1];
  char* Bs0 = (char*)Bs[0];
  char* Bs1 = (char*)Bs[1];
  const int ldst = wave * 1024;

  const int NT = K / 64;   // K-tiles (K=768 -> 12)
  const int NI = K / 128;  // loop iterations, 2 K-tiles each (-> 6)

  // One stage unit: quarter-tile u (64 rows) of K-tile t.
  auto stA = [&](char* dst, int t, int u) {
    if (t < NT)
      gload16(Ab + aoff + (long)t * 128 + (long)u * arow64,
              dst + u * 8192 + ldst);
  };
  auto stB = [&](char* dst, int t, int u) {
    if (t < NT)
      gload16(Bb + boff + (long)t * 128 + (long)u * brow64,
              dst + u * 8192 + ldst);
  };

  const int sw = (l16 & 7) << 4;
  auto rdA = [&](const char* buf, int ih, bf16x8 (&af)[4][2]) {
#pragma unroll
    for (int ii = 0; ii < 4; ++ii)
#pragma unroll
      for (int kk = 0; kk < 2; ++kk)
        af[ii][kk] = *(const bf16x8*)(buf +
            (wm * 128 + ih * 64 + ii * 16 + l16) * 128 +
            ((kk * 64 + lq * 16) ^ sw));
  };
  auto rdB = [&](const char* buf, int jh, bf16x8 (&bfh)[2][2]) {
#pragma unroll
    for (int jj = 0; jj < 2; ++jj)
#pragma unroll
      for (int kk = 0; kk < 2; ++kk)
        bfh[jj][kk] = *(const bf16x8*)(buf +
            (wn * 64 + (jh * 2 + jj) * 16 + l16) * 128 +
            ((kk * 64 + lq * 16) ^ sw));
  };

  f32x4 acc[8][4] = {};
  bf16x8 af[4][2], bf0[2][2], bf1[2][2];

  // Prologue: A(0) x4, B(0) x4, A(1)u0  (9 units in flight).
  stA(As0, 0, 0); stA(As0, 0, 1); stA(As0, 0, 2); stA(As0, 0, 3);
  stB(Bs0, 0, 0); stB(Bs0, 0, 1); stB(Bs0, 0, 2); stB(Bs0, 0, 3);
  stA(As1, 1, 0);

  for (int I = 0; I < NI; ++I) {
    const int b = 2 * I + 1, a2 = 2 * I + 2, b2 = 2 * I + 3;
    const bool last = (I == NI - 1);

    // ---- tile a = 2I (buf0) ----
    // ph0: needs A(a),B(a) done; newest-needed B(a)u3 has 3 units after it.
    stA(As1, b, 1); stB(Bs1, b, 0);
    VMW3();
    SBAR();
    rdA(As0, 0, af);
    rdB(Bs0, 0, bf0);
    mmaQ<0, 0>(acc, af, bf0);
    SBAR();
    // ph1
    stA(As1, b, 2); stB(Bs1, b, 1);
    rdB(Bs0, 1, bf1);
    SBAR();
    mmaQ<0, 1>(acc, af, bf1);
    SBAR();
    // ph2 (last LDS read of buf0.A)
    stA(As1, b, 3); stB(Bs1, b, 2);
    rdA(As0, 1, af);
    SBAR();
    mmaQ<1, 1>(acc, af, bf1);
    SBAR();
    // ph3 (buf0.A writable now; B(b)u3 issued BEFORE A(a2)u0 for vmcnt calc)
    stB(Bs1, b, 3); stA(As0, a2, 0);
    SBAR();
    mmaQ<1, 0>(acc, af, bf0);
    SBAR();

    // ---- tile b = 2I+1 (buf1) ----
    // ph4: needs A(b),B(b) done; newest-needed B(b)u3 has 3 units after it.
    stA(As0, a2, 1); stB(Bs0, a2, 0);
    if (last) { VMW0(); } else { VMW3(); }
    SBAR();
    rdA(As1, 0, af);
    rdB(Bs1, 0, bf0);
    mmaQ<0, 0>(acc, af, bf0);
    SBAR();
    // ph5
    stA(As0, a2, 2); stB(Bs0, a2, 1);
    rdB(Bs1, 1, bf1);
    SBAR();
    mmaQ<0, 1>(acc, af, bf1);
    SBAR();
    // ph6 (last LDS read of buf1.A)
    stA(As0, a2, 3); stB(Bs0, a2, 2);
    rdA(As1, 1, af);
    SBAR();
    mmaQ<1, 1>(acc, af, bf1);
    SBAR();
    // ph7 (B(a2)u3 BEFORE A(b2)u0 for next ph0's vmcnt calc)
    stB(Bs0, a2, 3); stA(As1, b2, 0);
    SBAR();
    mmaQ<1, 0>(acc, af, bf0);
    SBAR();
  }

  // Epilogue: P = exp2(acc*scale) packed us4; rowsum over k -> Lsum[q].
  // Lred aliases As (dead after the loop; vmcnt queue drained by last VMW0).
  float* Lred = (float*)As0;
  const long base_k = tileM + wm * 128;
  const long base_q = tileN + wn * 64;
  bf16* P = Pout + (long)bz * sC;
  float ps[4] = {0.f, 0.f, 0.f, 0.f};
#pragma unroll
  for (int j = 0; j < 4; ++j) {
    const long colq = base_q + j * 16 + l16;
#pragma unroll
    for (int i = 0; i < 8; ++i) {
      const long krow = base_k + i * 16 + lq * 4;
      const float p0 = exp2f(acc[i][j][0] * scale);
      const float p1 = exp2f(acc[i][j][1] * scale);
      const float p2 = exp2f(acc[i][j][2] * scale);
      const float p3 = exp2f(acc[i][j][3] * scale);
      ps[j] += (p0 + p1) + (p2 + p3);
      us4 w = {bfb(p0), bfb(p1), bfb(p2), bfb(p3)};
      *(us4*)(P + colq * (long)ldc + krow) = w;
    }
  }
  if (tid < 256) Lred[tid] = 0.f;
  __syncthreads();
#pragma unroll
  for (int j = 0; j < 4; ++j) {
    float v = ps[j];
    v += __shfl_xor(v, 16);
    v += __shfl_xor(v, 32);
    if (lq == 0) atomicAdd(&Lred[wn * 64 + j * 16 + l16], v);
  }
  __syncthreads();
  if (tid < 256) atomicAdd(&Lsum[(long)bz * TT + tileN + tid], Lred[tid]);
}

// ---------------------------------------------------------------------------
// Generic batched GEMM: C[z] = A[z][M x K] * B[z][N x K]^T  (bf16 in)
// 128x128 tile per block, 256 threads = 4 waves (2x2), each wave 64x64
// (4x4 frags of 16x16x32). BK=64, swizzled LDS (conflict-free ds_read_b128).
// acc layout: rows (M dim) = quad*4+reg (4 consecutive), cols (N dim)=lane&15.
// All epilogues store OUTPUT[col][row] so the 4 regs pack into one 8B store.
// SWZ: 1 = n-fastest XCD swizzle; 2 = m-fastest.
// MODE 3: h[col][row] = relu(acc + bias[row]), bf16
// MODE 4: out[col][row] = acc + bias[row] + resid[col][row], fp32 (float4, nt)
// MODE 7: split-K partial O[col][row] = acc (bf16, unnormalized); bz encodes
//         z = bz&3, kz = bz>>2; K columns offset by kz*2048; output buffer
//         offset kz * ROWS*DDIM elements (two adjacent 25.2MB buffers).
// ---------------------------------------------------------------------------
template <int MODE, int SWZ, int NT, int MT>
__global__ __launch_bounds__(256) void gemm_bt(
    const bf16* __restrict__ A, int lda, long sA,
    const bf16* __restrict__ B, int ldb, long sB,
    void* __restrict__ Cout, int ldc, long sC, int K, float scale,
    const float* __restrict__ bias, const float* __restrict__ resid,
    float* __restrict__ Lsum) {
  __shared__ __align__(16) bf16 As[128 * 64];   // 16 KB
  __shared__ __align__(16) bf16 Bs[128 * 64];   // 16 KB

  int bx, by, bz;
  if constexpr (SWZ == 1) {
    const int h   = blockIdx.x;
    const int xcd = h & 7;
    const int s   = h >> 3;
    bx = s % NT;                           // n cycles fastest within an XCD
    const int g = (s / NT) * 8 + xcd;      // (m,z) group pinned to this XCD
    by = g % MT;
    bz = g / MT;
  } else {
    const int h   = blockIdx.x;
    const int xcd = h & 7;
    const int s   = h >> 3;
    by = s % MT;                           // m cycles fastest within an XCD
    const int g = (s / MT) * 8 + xcd;      // (n,z) group pinned to this XCD
    bx = g % NT;
    bz = g / NT;
  }

  int kz = 0;
  if constexpr (MODE == 7) { kz = bz >> 2; bz &= 3; }

  A += (long)bz * sA + (long)kz * 2048;
  B += (long)bz * sB + (long)kz * 2048;

  const int tid  = threadIdx.x;        // 0..255
  const int wave = tid >> 6;           // 0..3
  const int lane = tid & 63;
  const int l16  = lane & 15;
  const int lq   = lane >> 4;          // quad 0..3
  const int wm   = wave >> 1;          // wave row 0..1
  const int wn   = wave & 1;           // wave col 0..1
  const long tileM = (long)by * 128;
  const long tileN = (long)bx * 128;

  f32x4 acc[4][4] = {};

  // Staging: 16 chunks of 1KB per 16KB tile; chunk = q*4 + wave. Physical LDS
  // is linear; the swizzle lives in the global SOURCE address (involution:
  // byte ^= ((row&7)<<4); rows are 128B).
  unsigned int aoff[4], boff[4];
#pragma unroll
  for (int q = 0; q < 4; ++q) {
    const int p    = (q * 4 + wave) * 1024 + lane * 16;  // phys byte in tile
    const int lg   = p ^ (((p >> 7) & 7) << 4);          // logical byte
    const int row  = lg >> 7;
    const int colb = lg & 127;
    aoff[q] = (unsigned int)((tileM + row) * (long)lda * 2 + colb);
    boff[q] = (unsigned int)((tileN + row) * (long)ldb * 2 + colb);
  }

  const char* Ab = (const char*)A;
  const char* Bb = (const char*)B;
  char* AsB = (char*)As;
  char* BsB = (char*)Bs;
  const int sw = (l16 & 7) << 4;

  for (int kb = 0; kb < K * 2; kb += 128) {   // byte offset along K
#pragma unroll
    for (int q = 0; q < 4; ++q)
      gload16(Ab + (aoff[q] + kb), AsB + (q * 4 + wave) * 1024);
#pragma unroll
    for (int q = 0; q < 4; ++q)
      gload16(Bb + (boff[q] + kb), BsB + (q * 4 + wave) * 1024);
    __syncthreads();

#pragma unroll
    for (int kk = 0; kk < 2; ++kk) {
      bf16x8 af[4], bf_[4];
      const int ks = (kk * 64 + lq * 16) ^ sw;
#pragma unroll
      for (int i = 0; i < 4; ++i)
        af[i] = *(const bf16x8*)(AsB + (wm * 64 + i * 16 + l16) * 128 + ks);
#pragma unroll
      for (int j = 0; j < 4; ++j)
        bf_[j] = *(const bf16x8*)(BsB + (wn * 64 + j * 16 + l16) * 128 + ks);
#pragma unroll
      for (int i = 0; i < 4; ++i)
#pragma unroll
        for (int j = 0; j < 4; ++j)
          acc[i][j] = __builtin_amdgcn_mfma_f32_16x16x32_bf16(af[i], bf_[j],
                                                              acc[i][j], 0, 0, 0);
    }
    __syncthreads();
  }

  const long base_m = tileM + wm * 64;   // acc row dim (A rows)
  const long base_n = tileN + wn * 64;   // acc col dim (B rows)

  if constexpr (MODE == 7) {
    // A=Vt (rows=d), B=P (rows=q). Partial O[q][d] = acc (no normalize);
    // output buffer selected by kz (two adjacent ROWS*DDIM bf16 buffers).
    bf16* Op = (bf16*)Cout + (long)kz * ((long)ROWS * DDIM) + (long)bz * sC;
#pragma unroll
    for (int j = 0; j < 4; ++j) {
      const long colq = base_n + j * 16 + l16;
#pragma unroll
      for (int i = 0; i < 4; ++i) {
        const long drow = base_m + i * 16 + lq * 4;
        us4 w = {bfb(acc[i][j][0]), bfb(acc[i][j][1]),
                 bfb(acc[i][j][2]), bfb(acc[i][j][3])};
        *(us4*)(Op + colq * (long)ldc + drow) = w;
      }
    }
  } else if constexpr (MODE == 3) {
    // A=W (rows=out_d), B=activations (rows=token). h[tok][d]=relu(acc+b[d])
    bf16* Hp = (bf16*)Cout;
#pragma unroll
    for (int i = 0; i < 4; ++i) {
      const long drow = base_m + i * 16 + lq * 4;
      const f32x4 bv = *(const f32x4*)&bias[drow];
#pragma unroll
      for (int j = 0; j < 4; ++j) {
        const long colt = base_n + j * 16 + l16;
        float v0 = acc[i][j][0] + bv[0]; v0 = v0 > 0.f ? v0 : 0.f;
        float v1 = acc[i][j][1] + bv[1]; v1 = v1 > 0.f ? v1 : 0.f;
        float v2 = acc[i][j][2] + bv[2]; v2 = v2 > 0.f ? v2 : 0.f;
        float v3 = acc[i][j][3] + bv[3]; v3 = v3 > 0.f ? v3 : 0.f;
        us4 w = {bfb(v0), bfb(v1), bfb(v2), bfb(v3)};
        *(us4*)(Hp + colt * (long)ldc + drow) = w;
      }
    }
  } else {  // MODE 4
    // out[tok][d] = acc + bias[d] + resid[tok][d], fp32, float4 stores (nt:
    // 4 quad-lanes x 16B = full 64B line per row per instruction)
    float* Op = (float*)Cout;
#pragma unroll
    for (int i = 0; i < 4; ++i) {
      const long drow = base_m + i * 16 + lq * 4;
      const f32x4 bv = *(const f32x4*)&bias[drow];
#pragma unroll
      for (int j = 0; j < 4; ++j) {
        const long off = (base_n + j * 16 + l16) * (long)ldc + drow;
        const f32x4 rs = *(const f32x4*)&resid[off];
        f32x4 o;
        o[0] = acc[i][j][0] + bv[0] + rs[0];
        o[1] = acc[i][j][1] + bv[1] + rs[1];
        o[2] = acc[i][j][2] + bv[2] + rs[2];
        o[3] = acc[i][j][3] + bv[3] + rs[3];
        __builtin_nontemporal_store(o, (f32x4*)(Op + off));
      }
    }
  }
}

// ---------------------------------------------------------------------------
// Fused QKV projection: grid.z selects {Q, K, V}. z=0,1: A=y1 (rows=token),
// B=W, plain store to Qm/Km. z=2: OPERANDS SWAPPED (A=Wv rows=out_d, B=y1)
// so Vt[d][tok] is written with tok as the lane-contiguous dim (coalesced).
// Same 4-wave / BK=64 / swizzled-LDS structure as gemm_bt.
// ---------------------------------------------------------------------------
__global__ __launch_bounds__(256) void gemm_qkv(
    const bf16* __restrict__ Y,
    const bf16* __restrict__ Wq, const bf16* __restrict__ Wk,
    const bf16* __restrict__ Wv, bf16* __restrict__ Qm,
    bf16* __restrict__ Km, bf16* __restrict__ Vt) {
  __shared__ __align__(16) bf16 As[128 * 64];
  __shared__ __align__(16) bf16 Bs[128 * 64];

  const int z = blockIdx.z;
  const bf16* Ap = (z == 2) ? Wv : Y;
  const bf16* Bp = (z == 0) ? Wq : (z == 1) ? Wk : Y;

  const int tid  = threadIdx.x;
  const int wave = tid >> 6;
  const int lane = tid & 63;
  const int l16  = lane & 15;
  const int lq   = lane >> 4;
  const int wm   = wave >> 1;
  const int wn   = wave & 1;
  const long tileM = (z == 2) ? (long)blockIdx.x * 128 : (long)blockIdx.y * 128;
  const long tileN = (z == 2) ? (long)blockIdx.y * 128 : (long)blockIdx.x * 128;

  unsigned int aoff[4], boff[4];
#pragma unroll
  for (int q = 0; q < 4; ++q) {
    const int p    = (q * 4 + wave) * 1024 + lane * 16;
    const int lg   = p ^ (((p >> 7) & 7) << 4);
    const int row  = lg >> 7;
    const int colb = lg & 127;
    aoff[q] = (unsigned int)((tileM + row) * (long)DDIM * 2 + colb);
    boff[q] = (unsigned int)((tileN + row) * (long)DDIM * 2 + colb);
  }

  f32x4 acc[4][4] = {};

  const char* Ab = (const char*)Ap;
  const char* Bb = (const char*)Bp;
  char* AsB = (char*)As;
  char* BsB = (char*)Bs;
  const int sw = (l16 & 7) << 4;

  for (int kb = 0; kb < DDIM * 2; kb += 128) {
#pragma unroll
    for (int q = 0; q < 4; ++q)
      gload16(Ab + (aoff[q] + kb), AsB + (q * 4 + wave) * 1024);
#pragma unroll
    for (int q = 0; q < 4; ++q)
      gload16(Bb + (boff[q] + kb), BsB + (q * 4 + wave) * 1024);
    __syncthreads();

#pragma unroll
    for (int kk = 0; kk < 2; ++kk) {
      bf16x8 af[4], bf_[4];
      const int ks = (kk * 64 + lq * 16) ^ sw;
#pragma unroll
      for (int i = 0; i < 4; ++i)
        af[i] = *(const bf16x8*)(AsB + (wm * 64 + i * 16 + l16) * 128 + ks);
#pragma unroll
      for (int j = 0; j < 4; ++j)
        bf_[j] = *(const bf16x8*)(BsB + (wn * 64 + j * 16 + l16) * 128 + ks);
#pragma unroll
      for (int i = 0; i < 4; ++i)
#pragma unroll
        for (int j = 0; j < 4; ++j)
          acc[i][j] = __builtin_amdgcn_mfma_f32_16x16x32_bf16(af[i], bf_[j],
                                                              acc[i][j], 0, 0, 0);
    }
    __syncthreads();
  }

  const long base_m = tileM + wm * 64;
  const long base_n = tileN + wn * 64;
  bf16* Cp = (z == 0) ? Qm : (z == 1) ? Km : Vt;
  const long ldo = (z < 2) ? (long)DDIM : (long)ROWS;
#pragma unroll
  for (int i = 0; i < 4; ++i)
#pragma unroll
    for (int j = 0; j < 4; ++j)
#pragma unroll
      for (int r = 0; r < 4; ++r) {
        const long row = base_m + i * 16 + lq * 4 + r;
        const long col = base_n + j * 16 + l16;
        Cp[row * ldo + col] = __float2bfloat16(acc[i][j][r]);
      }
}

// ---------------------------------------------------------------------------
// LayerNorm (faithful to buggy reference): y = (x - mu/sqrt(var)) * g + b,
// var unbiased (ddof=1). One block (256 thr) per 768-element row. Out bf16.
// DUAL=1: element = (in[i] + in2[i]) / Ldiv[row]  (split-K PV merge + softmax
// normalize, fused ahead of the stats). Optionally zeroes Lzero[row].
// ---------------------------------------------------------------------------
template <typename T, int DUAL>
__global__ __launch_bounds__(256) void ln_kernel(
    const T* __restrict__ in, const T* __restrict__ in2,
    const float* __restrict__ Ldiv, const float* __restrict__ g,
    const float* __restrict__ beta, bf16* __restrict__ out,
    float* __restrict__ Lzero) {
  const long row = blockIdx.x;
  if (Lzero != nullptr && threadIdx.x == 0) Lzero[row] = 0.f;
  const T* xr = in + row * DDIM;
  const int t = threadIdx.x;
  float v0 = to_f(xr[t]), v1 = to_f(xr[t + 256]), v2 = to_f(xr[t + 512]);
  if constexpr (DUAL) {
    const T* xr2 = in2 + row * DDIM;
    v0 += to_f(xr2[t]); v1 += to_f(xr2[t + 256]); v2 += to_f(xr2[t + 512]);
    const float invL = 1.0f / Ldiv[row];
    v0 *= invL; v1 *= invL; v2 *= invL;
  }
  float s = v0 + v1 + v2;
  float q = v0 * v0 + v1 * v1 + v2 * v2;
#pragma unroll
  for (int o = 32; o; o >>= 1) {
    s += __shfl_down(s, o);
    q += __shfl_down(q, o);
  }
  __shared__ float sb[4], qb[4];
  if ((t & 63) == 0) { sb[t >> 6] = s; qb[t >> 6] = q; }
  __syncthreads();
  const float S = sb[0] + sb[1] + sb[2] + sb[3];
  const float Q = qb[0] + qb[1] + qb[2] + qb[3];
  const float mu  = S * (1.0f / 768.0f);
  const float var = (Q - 768.0f * mu * mu) * (1.0f / 767.0f);
  const float sub = mu / sqrtf(var);
  bf16* orow = out + row * DDIM;
  orow[t]       = __float2bfloat16((v0 - sub) * g[t]       + beta[t]);
  orow[t + 256] = __float2bfloat16((v1 - sub) * g[t + 256] + beta[t + 256]);
  orow[t + 512] = __float2bfloat16((v2 - sub) * g[t + 512] + beta[t + 512]);
}

// ---------------------------------------------------------------------------
// Weight prep: z=0..2 transpose+cast wq/wk/wv (K x N -> N x K bf16),
// z=3..4 straight cast fc1_w/fc2_w (already N x K).
// block (32,8), grid (24,24,5)
// ---------------------------------------------------------------------------
__global__ void prep_weights(const float* __restrict__ wq,
                             const float* __restrict__ wk,
                             const float* __restrict__ wv,
                             const float* __restrict__ f1,
                             const float* __restrict__ f2,
                             bf16* wqt, bf16* wkt, bf16* wvt, bf16* f1b,
                             bf16* f2b) {
  __shared__ float tile[32][33];
  const float* src;
  bf16* dst;
  bool tr = true;
  switch (blockIdx.z) {
    case 0: src = wq; dst = wqt; break;
    case 1: src = wk; dst = wkt; break;
    case 2: src = wv; dst = wvt; break;
    case 3: src = f1; dst = f1b; tr = false; break;
    default: src = f2; dst = f2b; tr = false; break;
  }
  const int tx = threadIdx.x, ty = threadIdx.y;
  const int x = blockIdx.x * 32 + tx;
  const int y = blockIdx.y * 32 + ty;
  if (tr) {
#pragma unroll
    for (int r = 0; r < 4; ++r) tile[ty + 8 * r][tx] = src[(y + 8 * r) * DDIM + x];
    __syncthreads();
    const int ox = blockIdx.y * 32 + tx;
    const int oy = blockIdx.x * 32 + ty;
#pragma unroll
    for (int r = 0; r < 4; ++r)
      dst[(oy + 8 * r) * DDIM + ox] = __float2bfloat16(tile[tx][ty + 8 * r]);
  } else {
#pragma unroll
    for (int r = 0; r < 4; ++r)
      dst[(y + 8 * r) * DDIM + x] = __float2bfloat16(src[(y + 8 * r) * DDIM + x]);
  }
}

// ---------------------------------------------------------------------------
extern "C" void kernel_launch(void* const* d_in, const int* in_sizes, int n_in,
                              void* d_out, int out_size, void* d_ws,
                              size_t ws_size, hipStream_t stream) {
  const float* x     = (const float*)d_in[0];
  const float* ln1_g = (const float*)d_in[1];
  const float* ln1_b = (const float*)d_in[2];
  const float* wq    = (const float*)d_in[3];
  const float* wk    = (const float*)d_in[4];
  const float* wv    = (const float*)d_in[5];
  const float* ln2_g = (const float*)d_in[6];
  const float* ln2_b = (const float*)d_in[7];
  const float* f1w   = (const float*)d_in[8];
  const float* f1bias= (const float*)d_in[9];
  const float* f2w   = (const float*)d_in[10];
  const float* f2bias= (const float*)d_in[11];
  float* out = (float*)d_out;

  char* ws = (char*)d_ws;
  size_t off = 0;
  auto take = [&](size_t bytes) -> char* {
    char* p = ws + off;
    off += (bytes + 255) & ~(size_t)255;
    return p;
  };
  const size_t WB = (size_t)DDIM * DDIM * sizeof(bf16);   // 1.18 MB
  const size_t MB = (size_t)ROWS * DDIM * sizeof(bf16);   // 25.2 MB
  bf16* wqt = (bf16*)take(WB);
  bf16* wkt = (bf16*)take(WB);
  bf16* wvt = (bf16*)take(WB);
  bf16* f1b = (bf16*)take(WB);
  bf16* f2b = (bf16*)take(WB);
  float* Lsum = (float*)take((size_t)ROWS * sizeof(float));  // softmax row sums
  bf16* y1  = (bf16*)take(MB);
  bf16* Qm  = (bf16*)take(MB);   // NOTE: adjacent to y1 (MB is 256-aligned)
  bf16* Km  = (bf16*)take(MB);
  bf16* Vt  = (bf16*)take(MB);                              // V^T: 768 x 16384
  bf16* Sb  = (bf16*)take((size_t)NB * TT * TT * sizeof(bf16));  // 134 MB (P)
  // buffer reuse (strictly sequential stream):
  //   PV split-K partials: O0 = y1 (dead after QKV), O1 = Qm (dead after QK^T)
  //   LN2 reads y1+Qm (fused /Lsum), writes y2 = Km (dead after QK^T)
  //   MLP hidden h = y1 (dead after LN2)
  bf16* O0 = y1;
  bf16* O1 = Qm;   // must be y1 + ROWS*DDIM elements (verified by layout)
  bf16* y2 = Km;
  bf16* h  = y1;

  prep_weights<<<dim3(24, 24, 5), dim3(32, 8), 0, stream>>>(
      wq, wk, wv, f1w, f2w, wqt, wkt, wvt, f1b, f2b);

  // LN1 also zeroes Lsum (must precede QK^T; ws is re-poisoned every call)
  ln_kernel<float, 0><<<ROWS, 256, 0, stream>>>(x, nullptr, nullptr, ln1_g,
                                                ln1_b, y1, Lsum);

  // Fused QKV projections, 2304 blocks (z=2 operand-swapped for Vt)
  gemm_qkv<<<dim3(6, 128, 3), 256, 0, stream>>>(y1, wqt, wkt, wvt, Qm, Km, Vt);

  // scale folded with log2(e): P = exp2(log2e/sqrt(768) * K Q^T)
  const float scale2 = 0.03608439182435161f * 1.4426950408889634f;
  // 8-phase 256^2 QK^T: A=K (rows=k), B=Q (rows=q). 16x16x4 = 1024 blocks.
  gemm_qk8<<<dim3(16 * 16 * NB), 512, 0, stream>>>(
      Km, DDIM, (long)TT * DDIM, Qm, DDIM, (long)TT * DDIM, Sb, TT,
      (long)TT * TT, DDIM, scale2, Lsum);

  // SPLIT-K PV: A=Vt (rows=d), B=P (rows=q); 2 K-halves x (6 m x 32 n x 4 z)
  // = 1536 blocks (6/CU). Partial O -> O0/O1 (unnormalized bf16).
  // m-fastest swizzle: P q-tile pinned per XCD group, Vt d-tiles cycle.
  gemm_bt<7, 2, 32, 6><<<dim3(6 * 32 * NB * 2), 256, 0, stream>>>(
      Vt, ROWS, (long)TT, Sb, TT, (long)TT * TT, O0, DDIM, (long)TT * DDIM,
      TT / 2, 1.f, nullptr, nullptr, nullptr);

  // LN2 fuses (O0 + O1) / Lsum ahead of the stats.
  ln_kernel<bf16, 1><<<ROWS, 256, 0, stream>>>(O0, O1, Lsum, ln2_g, ln2_b, y2,
                                               nullptr);

  // MLP, SWAPPED (A=weight rows=out_d, B=activation rows=token).
  // m-fastest swizzle: activation tile pinned in L2, weight tiles cycle.
  gemm_bt<3, 2, 128, 6><<<dim3(128 * 6), 256, 0, stream>>>(
      f1b, DDIM, 0, y2, DDIM, 0, h, DDIM, 0, DDIM, 1.f, f1bias, nullptr,
      nullptr);
  gemm_bt<4, 2, 128, 6><<<dim3(128 * 6), 256, 0, stream>>>(
      f2b, DDIM, 0, h, DDIM, 0, out, DDIM, 0, DDIM, 1.f, f2bias, x, nullptr);
}